// Round 2
// baseline (515.930 us; speedup 1.0000x reference)
//
#include <hip/hip_runtime.h>
#include <cstdint>

typedef unsigned short u16;
typedef __bf16 bf16x8 __attribute__((ext_vector_type(8)));
typedef float f32x4 __attribute__((ext_vector_type(4)));
typedef int   i32x4 __attribute__((ext_vector_type(4)));
typedef u16   u16x4 __attribute__((ext_vector_type(4)));

#define M_DIM 8192   // B*S = 4*2048
#define N_DIM 4096   // UNITS
#define K_DIM 4096   // D

#define GLOBAL_AS(p) ((const __attribute__((address_space(1))) void*)(p))
#define LDS_AS(p)    ((__attribute__((address_space(3))) void*)(p))

// ---------- fp32 -> bf16 bits, round-to-nearest-even ----------
__device__ __forceinline__ u16 f2bf(float f) {
    union { float f; uint32_t u; } x; x.f = f;
    uint32_t u = x.u;
    uint32_t r = (u + 0x7fffu + ((u >> 16) & 1u)) >> 16;
    return (u16)r;
}

// ---------- fused prepass: unchanged (W-transpose + X-convert) ----------
__global__ __launch_bounds__(256) void prepass_kernel(const float* __restrict__ X,
                                                      const int* __restrict__ W,
                                                      u16* __restrict__ Xb,
                                                      u16* __restrict__ Wt) {
    const int bid = blockIdx.x;
    const int t   = threadIdx.x;
    if (bid < 4096) {
        __shared__ int tile[64][65];
        const int n0 = (bid & 63) * 64;
        const int k0 = (bid >> 6) * 64;
#pragma unroll
        for (int i = 0; i < 4; i++) {
            int e = t + i * 256;
            int r = e >> 4;
            int c = (e & 15) * 4;
            i32x4 v = __builtin_nontemporal_load(
                (const i32x4*)(W + (size_t)(k0 + r) * N_DIM + n0 + c));
            tile[r][c] = v.x; tile[r][c + 1] = v.y; tile[r][c + 2] = v.z; tile[r][c + 3] = v.w;
        }
        __syncthreads();
        {
            int n = t >> 2, ks = (t & 3) * 16;
            __align__(16) u16 o[16];
#pragma unroll
            for (int i = 0; i < 16; i++)
                o[i] = f2bf((float)tile[ks + i][n]);
            u16* dst = Wt + (size_t)(n0 + n) * K_DIM + k0 + ks;
            *(uint4*)(dst)     = *(const uint4*)&o[0];
            *(uint4*)(dst + 8) = *(const uint4*)&o[8];
        }
    } else {
        const size_t base = (size_t)(bid - 4096) * 4096;
        const f32x4*   x4 = (const f32x4*)X;
        u16x4*         o4 = (u16x4*)Xb;
#pragma unroll
        for (int it = 0; it < 8; it++) {
            size_t ia = base + (size_t)it * 512 + t;
            size_t ib = ia + 256;
            f32x4 a = __builtin_nontemporal_load(x4 + ia);
            f32x4 b = __builtin_nontemporal_load(x4 + ib);
            u16x4 oa, ob;
            oa.x = f2bf(a.x); oa.y = f2bf(a.y); oa.z = f2bf(a.z); oa.w = f2bf(a.w);
            ob.x = f2bf(b.x); ob.y = f2bf(b.y); ob.z = f2bf(b.z); ob.w = f2bf(b.w);
            o4[ia] = oa;
            o4[ib] = ob;
        }
    }
}

// =====================================================================
// 256x256 pipelined 4-phase GEMM (R1 post-mortem: reads serialized with
// MFMA -> 50% MfmaUtil matched 620/(620+reads+barriers) arithmetic).
// R2 change: frag ds_reads issued ONE PHASE AHEAD so LDS pipe overlaps
// matrix pipe; one barrier per phase (4/tile, was 9/tile).
//
// Per phase: BARRIER -> lgkmcnt(0) (drain prev phase's reads) ->
//            issue next-phase frag reads -> issue 1 half-tile stage ->
//            [vmcnt @ ph2] -> setprio(1) 16 MFMA setprio(0)
// Read schedule  (4/8/8/4): ph1: b1(T)   ph2: a1(T)   ph3: a0(T+1)  ph4: b0(T+1)
// Stage schedule (into buf b=T&1, tile T+2):
//                ph1: A_lo   ph2: B_lo   ph3: B_hi    ph4: A_hi
// Region safety (1-phase gap + per-phase lgkm drain + barrier), old-data
// last-read -> stage-issue: A_lo ph3(T-1)->ph1(T), B_lo ph4(T-1)->ph2(T),
// B_hi ph1(T)->ph3(T), A_hi ph2(T)->ph4(T). All barrier-separated after a
// full per-wave lgkmcnt(0) drain.
// vmcnt(4) @ ph2(T): T+1's 8 loads (issued during T-1) retired; 4 newer
// (A_lo,B_lo of T+2) stay in flight -> cross-tile prefetch reads at
// ph3/ph4 are safe after ph3's barrier.
// Register lifetimes (no double-buffering needed): a0 ph1-ph2, b0 ph1-ph3,
// b1 ph2-ph4, a1 ph3-ph4 -> prefetch writes (a0 @ph3, b0 @ph4) land in
// dead registers.
// =====================================================================

#define BK 64
#define NT (K_DIM / BK)
static_assert(NT >= 6 && (NT & 1) == 0, "tile count must be even and >= 6");

#define BARRIER() do { asm volatile("" ::: "memory"); \
                       __builtin_amdgcn_s_barrier();  \
                       asm volatile("" ::: "memory"); } while (0)
#define WAIT_LGKM() asm volatile("s_waitcnt lgkmcnt(0)" ::: "memory")
#define VMCNT(n)    asm volatile("s_waitcnt vmcnt(" #n ")" ::: "memory")

// read 4 m-frags x 2 k-steps (8 x ds_read_b128), swizzled
#define READ_A(dst, base, mhv)                                                    \
    _Pragma("unroll") for (int i = 0; i < 4; i++) {                               \
        const char* p_ = (base) + ((mhv) * 128 + wrow * 64 + i * 16 + fr) * 128;  \
        _Pragma("unroll") for (int kk = 0; kk < 2; kk++)                          \
            dst[i][kk] = *(const bf16x8*)(p_ + ((kk * 64 + fk2) ^ sw));           \
    }

// read 2 n-frags x 2 k-steps (4 x ds_read_b128), swizzled
#define READ_B(dst, base, nhv)                                                    \
    _Pragma("unroll") for (int j = 0; j < 2; j++) {                               \
        const char* p_ = (base) + ((nhv) * 128 + wcol * 32 + j * 16 + fr) * 128;  \
        _Pragma("unroll") for (int kk = 0; kk < 2; kk++)                          \
            dst[j][kk] = *(const bf16x8*)(p_ + ((kk * 64 + fk2) ^ sw));           \
    }

#define MFMA_Q(MH, NH, aarr, barr)                                                \
    do {                                                                          \
        __builtin_amdgcn_s_setprio(1);                                            \
        _Pragma("unroll") for (int kk = 0; kk < 2; kk++)                          \
            _Pragma("unroll") for (int i = 0; i < 4; i++)                         \
                _Pragma("unroll") for (int j = 0; j < 2; j++)                     \
                    acc[MH][NH][i][j] = __builtin_amdgcn_mfma_f32_16x16x32_bf16(  \
                        aarr[i][kk], barr[j][kk], acc[MH][NH][i][j], 0, 0, 0);    \
        __builtin_amdgcn_s_setprio(0);                                            \
    } while (0)

// stage one half-tile (128 rows x 64 cols bf16 = 16 KiB) = 2 x global_load_lds.
// LDS dest linear (wave-uniform base + lane*16); swizzle pre-applied to the
// per-lane GLOBAL source address (aoffN encodes chunk ^= row&7).
#define STAGE_A(bufv, h, kt)                                                      \
    do {                                                                          \
        const u16* g_ = gA + (size_t)(h) * (128 * K_DIM) + (size_t)(kt) * 64;     \
        char* l_ = (char*)lds + (bufv) * 32768 + (h) * 16384 + wv * 1024;         \
        __builtin_amdgcn_global_load_lds(GLOBAL_AS(g_ + aoff0), LDS_AS(l_), 16, 0, 0);        \
        __builtin_amdgcn_global_load_lds(GLOBAL_AS(g_ + aoff1), LDS_AS(l_ + 8192), 16, 0, 0); \
    } while (0)

#define STAGE_B(bufv, h, kt)                                                      \
    do {                                                                          \
        const u16* g_ = gB + (size_t)(h) * (128 * K_DIM) + (size_t)(kt) * 64;     \
        char* l_ = (char*)lds + 65536 + (bufv) * 32768 + (h) * 16384 + wv * 1024; \
        __builtin_amdgcn_global_load_lds(GLOBAL_AS(g_ + aoff0), LDS_AS(l_), 16, 0, 0);        \
        __builtin_amdgcn_global_load_lds(GLOBAL_AS(g_ + aoff1), LDS_AS(l_ + 8192), 16, 0, 0); \
    } while (0)

// one K-tile = 4 phases, one barrier per phase. S1..S4: stage statements,
// VM2: counted vmcnt placed in ph2, PRE: compile-time flag for cross-tile
// fragment prefetch (off only on the last tile).
#define TILE(bv, S1, S2, S3, S4, VM2, PRE)                                        \
    {                                                                             \
        const char* As_ = (const char*)lds + (bv) * 32768;                        \
        const char* Bs_ = (const char*)lds + 65536 + (bv) * 32768;                \
        const char* An_ = (const char*)lds + ((bv) ^ 1) * 32768;                  \
        const char* Bn_ = (const char*)lds + 65536 + ((bv) ^ 1) * 32768;          \
        /* ph1 */                                                                 \
        BARRIER(); WAIT_LGKM();                                                   \
        READ_B(b1, Bs_, 1);                                                       \
        S1;                                                                       \
        MFMA_Q(0, 0, a0, b0);                                                     \
        /* ph2 */                                                                 \
        BARRIER(); WAIT_LGKM();                                                   \
        READ_A(a1, As_, 1);                                                       \
        S2; VM2;                                                                  \
        MFMA_Q(0, 1, a0, b1);                                                     \
        /* ph3 */                                                                 \
        BARRIER(); WAIT_LGKM();                                                   \
        if (PRE) { READ_A(a0, An_, 0); }                                          \
        S3;                                                                       \
        MFMA_Q(1, 0, a1, b0);                                                     \
        /* ph4 */                                                                 \
        BARRIER(); WAIT_LGKM();                                                   \
        if (PRE) { READ_B(b0, Bn_, 0); }                                          \
        S4;                                                                       \
        MFMA_Q(1, 1, a1, b1);                                                     \
    }

__global__ __launch_bounds__(512, 2) void gemm_bf16_kernel(const u16* __restrict__ A,
                                                           const u16* __restrict__ Bt,
                                                           const float* __restrict__ scale_p,
                                                           float* __restrict__ C) {
    __shared__ __align__(16) u16 lds[65536];   // 128 KiB: A[2][256][64] | B[2][256][64]

    const int tid  = threadIdx.x;
    const int lane = tid & 63;
    const int wv   = tid >> 6;       // wave 0..7
    const int wrow = wv >> 2;        // 0..1  (M)
    const int wcol = wv & 3;         // 0..3  (N)

    // T1: bijective XCD swizzle, 512 blocks, 8 XCDs -> 64 blocks per XCD chunk
    const int bid = blockIdx.x;
    const int wg  = ((bid & 7) << 6) | (bid >> 3);
    const size_t m0 = (size_t)(wg >> 4) * 256;   // 32 M-tiles
    const size_t n0 = (size_t)(wg & 15) * 256;   // 16 N-tiles

    // fragment addressing: row r has swizzle XOR (r&7)<<4; frag rows are
    // multiple-of-16 + (lane&15) so the XOR is the per-lane constant sw.
    const int fr  = lane & 15;
    const int fk2 = (lane >> 4) * 16;            // k byte offset {0,16,32,48}
    const int sw  = (lane & 7) << 4;

    // staging: half-tile chunk q in {tid, tid+512}; row = q>>3,
    // global chunk = (q&7) ^ (row&7)  (inverse swizzle on the source side)
    const int q0 = tid,       r0 = q0 >> 3, c0 = (q0 & 7) ^ (r0 & 7);
    const int q1 = tid + 512, r1 = q1 >> 3, c1 = (q1 & 7) ^ (r1 & 7);
    const size_t aoff0 = (size_t)r0 * K_DIM + c0 * 8;
    const size_t aoff1 = (size_t)r1 * K_DIM + c1 * 8;

    const u16* gA = A  + m0 * K_DIM;
    const u16* gB = Bt + n0 * K_DIM;

    f32x4 acc[2][2][4][2] = {};
    bf16x8 a0[4][2], a1[4][2], b0[2][2], b1[2][2];

    // prologue: stage tiles 0 and 1 completely (16 loads)
    STAGE_A(0, 0, 0); STAGE_B(0, 0, 0); STAGE_B(0, 1, 0); STAGE_A(0, 1, 0);
    STAGE_A(1, 0, 1); STAGE_B(1, 0, 1); STAGE_B(1, 1, 1); STAGE_A(1, 1, 1);
    VMCNT(8);            // tile 0 landed; tile 1's 8 loads stay in flight
    BARRIER();
    {   // preload tile 0's ph1 fragments (a0 = A_lo, b0 = B_lo of buf 0)
        const char* As_ = (const char*)lds;
        const char* Bs_ = (const char*)lds + 65536;
        READ_A(a0, As_, 0);
        READ_B(b0, Bs_, 0);
    }
    WAIT_LGKM();         // drain prologue reads before any wave stages over A_lo/B_lo

    // main loop: tiles 0..NT-3, staging T+2/T+3; buffers alternate 0,1
    for (int T = 0; T < NT - 2; T += 2) {
        TILE(0,
             STAGE_A(0, 0, T + 2), STAGE_B(0, 0, T + 2),
             STAGE_B(0, 1, T + 2), STAGE_A(0, 1, T + 2),
             VMCNT(4), 1);
        TILE(1,
             STAGE_A(1, 0, T + 3), STAGE_B(1, 0, T + 3),
             STAGE_B(1, 1, T + 3), STAGE_A(1, 1, T + 3),
             VMCNT(4), 1);
    }
    // tile NT-2 (buf 0): nothing left to stage; drain so NT-1 is fully landed
    TILE(0, (void)0, (void)0, (void)0, (void)0, VMCNT(0), 1);
    // tile NT-1 (buf 1): pure compute, no prefetch
    TILE(1, (void)0, (void)0, (void)0, (void)0, (void)0, 0);

    // epilogue: D layout col = lane&15, row = (lane>>4)*4 + reg; NT stores
    const float s = *scale_p;
    const int ec = lane & 15;
    const int er = (lane >> 4) * 4;
#pragma unroll
    for (int mh = 0; mh < 2; mh++)
#pragma unroll
        for (int nh = 0; nh < 2; nh++)
#pragma unroll
            for (int i = 0; i < 4; i++)
#pragma unroll
                for (int j = 0; j < 2; j++) {
                    float* cp = C + (m0 + mh * 128 + wrow * 64 + i * 16 + er) * N_DIM
                                  + (n0 + nh * 128 + wcol * 32 + j * 16 + ec);
#pragma unroll
                    for (int r = 0; r < 4; r++)
                        __builtin_nontemporal_store(acc[mh][nh][i][j][r] * s,
                                                    cp + (size_t)r * N_DIM);
                }
}

// ---------- fallback fp32 GEMM (only if ws too small; correctness net) ----------
__global__ __launch_bounds__(256) void fb_gemm_kernel(const float* __restrict__ X,
                                                      const int* __restrict__ W,
                                                      const float* __restrict__ sp,
                                                      float* __restrict__ Y) {
    __shared__ float Xs[16][64];
    __shared__ float Ws[16][64];
    const int t = threadIdx.x;
    const int tx = t & 15, ty = t >> 4;
    const int m0 = blockIdx.y * 64, n0 = blockIdx.x * 64;
    float acc[4][4] = {};
    for (int k0 = 0; k0 < K_DIM; k0 += 16) {
#pragma unroll
        for (int i = 0; i < 4; i++) {
            int e = t + i * 256;
            int r = e >> 4, c = e & 15;
            Xs[c][r] = X[(size_t)(m0 + r) * K_DIM + k0 + c];
            int rw = e >> 6, cw = e & 63;
            Ws[rw][cw] = (float)W[(size_t)(k0 + rw) * N_DIM + n0 + cw];
        }
        __syncthreads();
#pragma unroll
        for (int kk = 0; kk < 16; kk++)
#pragma unroll
            for (int i = 0; i < 4; i++)
#pragma unroll
                for (int j = 0; j < 4; j++)
                    acc[i][j] += Xs[kk][ty * 4 + i] * Ws[kk][tx * 4 + j];
        __syncthreads();
    }
    const float s = *sp;
#pragma unroll
    for (int i = 0; i < 4; i++)
#pragma unroll
        for (int j = 0; j < 4; j++)
            Y[(size_t)(m0 + ty * 4 + i) * N_DIM + n0 + tx * 4 + j] = acc[i][j] * s;
}

extern "C" void kernel_launch(void* const* d_in, const int* in_sizes, int n_in,
                              void* d_out, int out_size, void* d_ws, size_t ws_size,
                              hipStream_t stream) {
    const float* X  = (const float*)d_in[0];
    const int*   W  = (const int*)d_in[1];
    const float* sp = (const float*)d_in[2];
    float* Y = (float*)d_out;

    const size_t xb = (size_t)M_DIM * K_DIM * sizeof(u16);   // 64 MB
    const size_t wb = (size_t)N_DIM * K_DIM * sizeof(u16);   // 32 MB

    if (ws_size >= xb + wb) {
        u16* Xb = (u16*)d_ws;
        u16* Wt = (u16*)((char*)d_ws + xb);
        prepass_kernel<<<6144, 256, 0, stream>>>(X, W, Xb, Wt);
        gemm_bf16_kernel<<<512, 512, 0, stream>>>(Xb, Wt, sp, Y);
    } else {
        fb_gemm_kernel<<<dim3(N_DIM / 64, M_DIM / 64), 256, 0, stream>>>(X, W, sp, Y);
    }
}

// Round 3
// 513.589 us; speedup vs baseline: 1.0046x; 1.0046x over previous
//
#include <hip/hip_runtime.h>
#include <cstdint>

typedef unsigned short u16;
typedef __bf16 bf16x8 __attribute__((ext_vector_type(8)));
typedef float f32x4 __attribute__((ext_vector_type(4)));
typedef int   i32x4 __attribute__((ext_vector_type(4)));
typedef u16   u16x4 __attribute__((ext_vector_type(4)));

#define M_DIM 8192   // B*S = 4*2048
#define N_DIM 4096   // UNITS
#define K_DIM 4096   // D

#define GLOBAL_AS(p) ((const __attribute__((address_space(1))) void*)(p))
#define LDS_AS(p)    ((__attribute__((address_space(3))) void*)(p))

// ---------- fp32 -> bf16 bits, round-to-nearest-even ----------
__device__ __forceinline__ u16 f2bf(float f) {
    union { float f; uint32_t u; } x; x.f = f;
    uint32_t u = x.u;
    uint32_t r = (u + 0x7fffu + ((u >> 16) & 1u)) >> 16;
    return (u16)r;
}

// ---------- prepass, SPLIT into two kernels for counter attribution ----------
// (R2 post-mortem: prepass ~220us for 288MB = 1.3 TB/s, 4.5x off roofline,
//  but never surfaces in top-5 counters. Identical logic, two dispatches.)

// W (K,N) int32 -> Wt (N,K) bf16, 64x64 tile per block, 4096 blocks
__global__ __launch_bounds__(256) void prepass_w_kernel(const int* __restrict__ W,
                                                        u16* __restrict__ Wt) {
    const int bid = blockIdx.x;
    const int t   = threadIdx.x;
    __shared__ int tile[64][65];
    const int n0 = (bid & 63) * 64;
    const int k0 = (bid >> 6) * 64;
#pragma unroll
    for (int i = 0; i < 4; i++) {
        int e = t + i * 256;
        int r = e >> 4;
        int c = (e & 15) * 4;
        i32x4 v = __builtin_nontemporal_load(
            (const i32x4*)(W + (size_t)(k0 + r) * N_DIM + n0 + c));
        tile[r][c] = v.x; tile[r][c + 1] = v.y; tile[r][c + 2] = v.z; tile[r][c + 3] = v.w;
    }
    __syncthreads();
    {
        int n = t >> 2, ks = (t & 3) * 16;
        __align__(16) u16 o[16];
#pragma unroll
        for (int i = 0; i < 16; i++)
            o[i] = f2bf((float)tile[ks + i][n]);
        u16* dst = Wt + (size_t)(n0 + n) * K_DIM + k0 + ks;
        *(uint4*)(dst)     = *(const uint4*)&o[0];
        *(uint4*)(dst + 8) = *(const uint4*)&o[8];
    }
}

// X fp32 -> bf16, 4096 float4-chunks per block, 2048 blocks, coalesced
__global__ __launch_bounds__(256) void prepass_x_kernel(const float* __restrict__ X,
                                                        u16* __restrict__ Xb) {
    const int t = threadIdx.x;
    const size_t base = (size_t)blockIdx.x * 4096;
    const f32x4* x4 = (const f32x4*)X;
    u16x4*       o4 = (u16x4*)Xb;
#pragma unroll
    for (int it = 0; it < 8; it++) {
        size_t ia = base + (size_t)it * 512 + t;
        size_t ib = ia + 256;
        f32x4 a = __builtin_nontemporal_load(x4 + ia);
        f32x4 b = __builtin_nontemporal_load(x4 + ib);
        u16x4 oa, ob;
        oa.x = f2bf(a.x); oa.y = f2bf(a.y); oa.z = f2bf(a.z); oa.w = f2bf(a.w);
        ob.x = f2bf(b.x); ob.y = f2bf(b.y); ob.z = f2bf(b.z); ob.w = f2bf(b.w);
        o4[ia] = oa;
        o4[ib] = ob;
    }
}

// =====================================================================
// 256x256 pipelined 4-phase GEMM, R3.
// R2 failed (41%) for two reasons, both fixed here:
//  (a) prefetch ds_reads + MFMAs shared one region with no ordering -> the
//      scheduler sank the reads to the region end (serialized again).
//      FIX: sched_barrier(0) between reads and MFMA pins reads FIRST, so
//      the matrix pipe (620cy) covers the LDS drain (~380-580cy).
//  (b) VMCNT(4) at ph2 waited on 1-phase-old loads (< HBM latency).
//      FIX: single VMCNT(4) per tile at ph3 -> waits only on loads >= 2
//      phases (~1300+cy) old. Prologue VMCNT(0) establishes the invariant.
//
// Phase p: BARRIER; lgkm0; [reads for phase p+1]; sched_barrier(0);
//          stage; [VMCNT(4) at p3]; 16 MFMA (operands read in phase p-1).
// Read schedule:  p1: b1(T)  p2: a1(T)  p3: a0(T+1)  p4: b0(T+1)
// Stage schedule (tile T+2, buf b=T&1): p1: A_lo  p2: B_lo  p3: B_hi  p4: A_hi
//
// Stale-read/overwrite safety (every pair barrier-separated after a full
// per-wave lgkm0 drain): A_lo read p3(T-1)->drain p4(T-1)->stage p1(T);
// B_lo p4(T-1)->p1(T)->p2(T); B_hi p1(T)->p2(T)->p3(T); A_hi p2(T)->p3(T)
// ->p4(T).  Landing guarantees (VMCNT(4)@p3(T) leaves only
// {B_lo(T+2),B_hi(T+2)} in flight): every read's data retired >=1 barrier
// before the read, verified tile-by-tile incl. prologue (VMCNT(0)) + tail.
// =====================================================================

#define BK 64
#define NT (K_DIM / BK)
static_assert(NT >= 6 && (NT & 1) == 0, "tile count must be even and >= 6");

#define BARRIER() do { asm volatile("" ::: "memory"); \
                       __builtin_amdgcn_s_barrier();  \
                       asm volatile("" ::: "memory"); } while (0)
#define WAIT_LGKM() asm volatile("s_waitcnt lgkmcnt(0)" ::: "memory")
#define VMCNT(n)    asm volatile("s_waitcnt vmcnt(" #n ")" ::: "memory")
#define SBAR0()     __builtin_amdgcn_sched_barrier(0)

// read 4 m-frags x 2 k-steps (8 x ds_read_b128), swizzled
#define READ_A(dst, base, mhv)                                                    \
    _Pragma("unroll") for (int i = 0; i < 4; i++) {                               \
        const char* p_ = (base) + ((mhv) * 128 + wrow * 64 + i * 16 + fr) * 128;  \
        _Pragma("unroll") for (int kk = 0; kk < 2; kk++)                          \
            dst[i][kk] = *(const bf16x8*)(p_ + ((kk * 64 + fk2) ^ sw));           \
    }

// read 2 n-frags x 2 k-steps (4 x ds_read_b128), swizzled
#define READ_B(dst, base, nhv)                                                    \
    _Pragma("unroll") for (int j = 0; j < 2; j++) {                               \
        const char* p_ = (base) + ((nhv) * 128 + wcol * 32 + j * 16 + fr) * 128;  \
        _Pragma("unroll") for (int kk = 0; kk < 2; kk++)                          \
            dst[j][kk] = *(const bf16x8*)(p_ + ((kk * 64 + fk2) ^ sw));           \
    }

#define MFMA_Q(MH, NH, aarr, barr)                                                \
    do {                                                                          \
        __builtin_amdgcn_s_setprio(1);                                            \
        _Pragma("unroll") for (int kk = 0; kk < 2; kk++)                          \
            _Pragma("unroll") for (int i = 0; i < 4; i++)                         \
                _Pragma("unroll") for (int j = 0; j < 2; j++)                     \
                    acc[MH][NH][i][j] = __builtin_amdgcn_mfma_f32_16x16x32_bf16(  \
                        aarr[i][kk], barr[j][kk], acc[MH][NH][i][j], 0, 0, 0);    \
        __builtin_amdgcn_s_setprio(0);                                            \
    } while (0)

// stage one half-tile (128 rows x 64 cols bf16 = 16 KiB) = 2 x global_load_lds.
// LDS dest linear (wave-uniform base + lane*16); swizzle pre-applied to the
// per-lane GLOBAL source address (aoffN encodes chunk ^= row&7).
#define STAGE_A(bufv, h, kt)                                                      \
    do {                                                                          \
        const u16* g_ = gA + (size_t)(h) * (128 * K_DIM) + (size_t)(kt) * 64;     \
        char* l_ = (char*)lds + (bufv) * 32768 + (h) * 16384 + wv * 1024;         \
        __builtin_amdgcn_global_load_lds(GLOBAL_AS(g_ + aoff0), LDS_AS(l_), 16, 0, 0);        \
        __builtin_amdgcn_global_load_lds(GLOBAL_AS(g_ + aoff1), LDS_AS(l_ + 8192), 16, 0, 0); \
    } while (0)

#define STAGE_B(bufv, h, kt)                                                      \
    do {                                                                          \
        const u16* g_ = gB + (size_t)(h) * (128 * K_DIM) + (size_t)(kt) * 64;     \
        char* l_ = (char*)lds + 65536 + (bufv) * 32768 + (h) * 16384 + wv * 1024; \
        __builtin_amdgcn_global_load_lds(GLOBAL_AS(g_ + aoff0), LDS_AS(l_), 16, 0, 0);        \
        __builtin_amdgcn_global_load_lds(GLOBAL_AS(g_ + aoff1), LDS_AS(l_ + 8192), 16, 0, 0); \
    } while (0)

// one K-tile = 4 phases, one barrier per phase. S1..S4: stage statements,
// VM3: counted vmcnt in p3, PRE: cross-tile frag prefetch (off on last tile).
#define TILE(bv, S1, S2, S3, S4, VM3, PRE)                                        \
    {                                                                             \
        const char* As_ = (const char*)lds + (bv) * 32768;                        \
        const char* Bs_ = (const char*)lds + 65536 + (bv) * 32768;                \
        const char* An_ = (const char*)lds + ((bv) ^ 1) * 32768;                  \
        const char* Bn_ = (const char*)lds + 65536 + ((bv) ^ 1) * 32768;          \
        /* p1 */                                                                  \
        BARRIER(); WAIT_LGKM();                                                   \
        READ_B(b1, Bs_, 1);                                                       \
        SBAR0();                                                                  \
        S1;                                                                       \
        MFMA_Q(0, 0, a0, b0);                                                     \
        /* p2 */                                                                  \
        BARRIER(); WAIT_LGKM();                                                   \
        READ_A(a1, As_, 1);                                                       \
        SBAR0();                                                                  \
        S2;                                                                       \
        MFMA_Q(0, 1, a0, b1);                                                     \
        /* p3 */                                                                  \
        BARRIER(); WAIT_LGKM();                                                   \
        if (PRE) { READ_A(a0, An_, 0); }                                          \
        SBAR0();                                                                  \
        S3; VM3;                                                                  \
        MFMA_Q(1, 0, a1, b0);                                                     \
        /* p4 */                                                                  \
        BARRIER(); WAIT_LGKM();                                                   \
        if (PRE) { READ_B(b0, Bn_, 0); }                                          \
        SBAR0();                                                                  \
        S4;                                                                       \
        MFMA_Q(1, 1, a1, b1);                                                     \
    }

__global__ __launch_bounds__(512, 2) void gemm_bf16_kernel(const u16* __restrict__ A,
                                                           const u16* __restrict__ Bt,
                                                           const float* __restrict__ scale_p,
                                                           float* __restrict__ C) {
    __shared__ __align__(16) u16 lds[65536];   // 128 KiB: A[2][256][64] | B[2][256][64]

    const int tid  = threadIdx.x;
    const int lane = tid & 63;
    const int wv   = tid >> 6;       // wave 0..7
    const int wrow = wv >> 2;        // 0..1  (M)
    const int wcol = wv & 3;         // 0..3  (N)

    // T1: bijective XCD swizzle, 512 blocks, 8 XCDs -> 64 blocks per XCD chunk
    const int bid = blockIdx.x;
    const int wg  = ((bid & 7) << 6) | (bid >> 3);
    const size_t m0 = (size_t)(wg >> 4) * 256;   // 32 M-tiles
    const size_t n0 = (size_t)(wg & 15) * 256;   // 16 N-tiles

    // fragment addressing: row r has swizzle XOR (r&7)<<4; frag rows are
    // multiple-of-16 + (lane&15) so the XOR is the per-lane constant sw.
    const int fr  = lane & 15;
    const int fk2 = (lane >> 4) * 16;            // k byte offset {0,16,32,48}
    const int sw  = (lane & 7) << 4;

    // staging: half-tile chunk q in {tid, tid+512}; row = q>>3,
    // global chunk = (q&7) ^ (row&7)  (inverse swizzle on the source side)
    const int q0 = tid,       r0 = q0 >> 3, c0 = (q0 & 7) ^ (r0 & 7);
    const int q1 = tid + 512, r1 = q1 >> 3, c1 = (q1 & 7) ^ (r1 & 7);
    const size_t aoff0 = (size_t)r0 * K_DIM + c0 * 8;
    const size_t aoff1 = (size_t)r1 * K_DIM + c1 * 8;

    const u16* gA = A  + m0 * K_DIM;
    const u16* gB = Bt + n0 * K_DIM;

    f32x4 acc[2][2][4][2] = {};
    bf16x8 a0[4][2], a1[4][2], b0[2][2], b1[2][2];

    // prologue: stage tiles 0 and 1 completely (16 loads), then full drain.
    // (VMCNT(0) here, not (8): p3(0)'s prefetch of a0(1) reads tile-1 data
    //  BEFORE p3's own vmcnt, so tile 1 must be landed from the start.)
    STAGE_A(0, 0, 0); STAGE_B(0, 0, 0); STAGE_B(0, 1, 0); STAGE_A(0, 1, 0);
    STAGE_A(1, 0, 1); STAGE_B(1, 0, 1); STAGE_B(1, 1, 1); STAGE_A(1, 1, 1);
    VMCNT(0);
    BARRIER();
    {   // preload tile 0's p1 fragments (a0 = A_lo, b0 = B_lo of buf 0)
        const char* As_ = (const char*)lds;
        const char* Bs_ = (const char*)lds + 65536;
        READ_A(a0, As_, 0);
        READ_B(b0, Bs_, 0);
    }
    WAIT_LGKM();   // drain preloads before any wave's p1 stage can overwrite A_lo

    // main loop: tiles 0..NT-3 in pairs, staging T+2/T+3
    for (int T = 0; T < NT - 2; T += 2) {
        TILE(0,
             STAGE_A(0, 0, T + 2), STAGE_B(0, 0, T + 2),
             STAGE_B(0, 1, T + 2), STAGE_A(0, 1, T + 2),
             VMCNT(4), 1);
        TILE(1,
             STAGE_A(1, 0, T + 3), STAGE_B(1, 0, T + 3),
             STAGE_B(1, 1, T + 3), STAGE_A(1, 1, T + 3),
             VMCNT(4), 1);
    }
    // tile NT-2 (buf 0): nothing to stage; full drain so tile NT-1 is landed
    TILE(0, (void)0, (void)0, (void)0, (void)0, VMCNT(0), 1);
    // tile NT-1 (buf 1): pure compute, no prefetch
    TILE(1, (void)0, (void)0, (void)0, (void)0, (void)0, 0);

    // epilogue: D layout col = lane&15, row = (lane>>4)*4 + reg; NT stores
    const float s = *scale_p;
    const int ec = lane & 15;
    const int er = (lane >> 4) * 4;
#pragma unroll
    for (int mh = 0; mh < 2; mh++)
#pragma unroll
        for (int nh = 0; nh < 2; nh++)
#pragma unroll
            for (int i = 0; i < 4; i++)
#pragma unroll
                for (int j = 0; j < 2; j++) {
                    float* cp = C + (m0 + mh * 128 + wrow * 64 + i * 16 + er) * N_DIM
                                  + (n0 + nh * 128 + wcol * 32 + j * 16 + ec);
#pragma unroll
                    for (int r = 0; r < 4; r++)
                        __builtin_nontemporal_store(acc[mh][nh][i][j][r] * s,
                                                    cp + (size_t)r * N_DIM);
                }
}

// ---------- fallback fp32 GEMM (only if ws too small; correctness net) ----------
__global__ __launch_bounds__(256) void fb_gemm_kernel(const float* __restrict__ X,
                                                      const int* __restrict__ W,
                                                      const float* __restrict__ sp,
                                                      float* __restrict__ Y) {
    __shared__ float Xs[16][64];
    __shared__ float Ws[16][64];
    const int t = threadIdx.x;
    const int tx = t & 15, ty = t >> 4;
    const int m0 = blockIdx.y * 64, n0 = blockIdx.x * 64;
    float acc[4][4] = {};
    for (int k0 = 0; k0 < K_DIM; k0 += 16) {
#pragma unroll
        for (int i = 0; i < 4; i++) {
            int e = t + i * 256;
            int r = e >> 4, c = e & 15;
            Xs[c][r] = X[(size_t)(m0 + r) * K_DIM + k0 + c];
            int rw = e >> 6, cw = e & 63;
            Ws[rw][cw] = (float)W[(size_t)(k0 + rw) * N_DIM + n0 + cw];
        }
        __syncthreads();
#pragma unroll
        for (int kk = 0; kk < 16; kk++)
#pragma unroll
            for (int i = 0; i < 4; i++)
#pragma unroll
                for (int j = 0; j < 4; j++)
                    acc[i][j] += Xs[kk][ty * 4 + i] * Ws[kk][tx * 4 + j];
        __syncthreads();
    }
    const float s = *sp;
#pragma unroll
    for (int i = 0; i < 4; i++)
#pragma unroll
        for (int j = 0; j < 4; j++)
            Y[(size_t)(m0 + ty * 4 + i) * N_DIM + n0 + tx * 4 + j] = acc[i][j] * s;
}

extern "C" void kernel_launch(void* const* d_in, const int* in_sizes, int n_in,
                              void* d_out, int out_size, void* d_ws, size_t ws_size,
                              hipStream_t stream) {
    const float* X  = (const float*)d_in[0];
    const int*   W  = (const int*)d_in[1];
    const float* sp = (const float*)d_in[2];
    float* Y = (float*)d_out;

    const size_t xb = (size_t)M_DIM * K_DIM * sizeof(u16);   // 64 MB
    const size_t wb = (size_t)N_DIM * K_DIM * sizeof(u16);   // 32 MB

    if (ws_size >= xb + wb) {
        u16* Xb = (u16*)d_ws;
        u16* Wt = (u16*)((char*)d_ws + xb);
        prepass_w_kernel<<<4096, 256, 0, stream>>>(W, Wt);
        prepass_x_kernel<<<2048, 256, 0, stream>>>(X, Xb);
        gemm_bf16_kernel<<<512, 512, 0, stream>>>(Xb, Wt, sp, Y);
    } else {
        fb_gemm_kernel<<<dim3(N_DIM / 64, M_DIM / 64), 256, 0, stream>>>(X, W, sp, Y);
    }
}

// Round 4
// 466.632 us; speedup vs baseline: 1.1056x; 1.1006x over previous
//
#include <hip/hip_runtime.h>
#include <cstdint>

typedef unsigned short u16;
typedef __bf16 bf16x8 __attribute__((ext_vector_type(8)));
typedef float f32x4 __attribute__((ext_vector_type(4)));
typedef int   i32x4 __attribute__((ext_vector_type(4)));
typedef u16   u16x4 __attribute__((ext_vector_type(4)));

#define M_DIM 8192   // B*S = 4*2048
#define N_DIM 4096   // UNITS
#define K_DIM 4096   // D

#define GLOBAL_AS(p) ((const __attribute__((address_space(1))) void*)(p))
#define LDS_AS(p)    ((__attribute__((address_space(3))) void*)(p))

// ---------- fp32 -> bf16 bits, round-to-nearest-even ----------
__device__ __forceinline__ u16 f2bf(float f) {
    union { float f; uint32_t u; } x; x.f = f;
    uint32_t u = x.u;
    uint32_t r = (u + 0x7fffu + ((u >> 16) & 1u)) >> 16;
    return (u16)r;
}

// ---------- fused prepass (R0 version, proven): W-transpose + X-convert ----------
// blocks [0,4096):  W (K,N) int32 -> Wt (N,K) bf16, 64x64 tile each (NT loads)
// blocks [4096,6144): X fp32 -> bf16, 4096 float4-chunks each, fully coalesced
__global__ __launch_bounds__(256) void prepass_kernel(const float* __restrict__ X,
                                                      const int* __restrict__ W,
                                                      u16* __restrict__ Xb,
                                                      u16* __restrict__ Wt) {
    const int bid = blockIdx.x;
    const int t   = threadIdx.x;
    if (bid < 4096) {
        __shared__ int tile[64][65];                  // +1 pad: conflict-free column reads
        const int n0 = (bid & 63) * 64;
        const int k0 = (bid >> 6) * 64;
#pragma unroll
        for (int i = 0; i < 4; i++) {
            int e = t + i * 256;                      // 1024 int4-chunks
            int r = e >> 4;                           // row 0..63
            int c = (e & 15) * 4;                     // col 0..60
            i32x4 v = __builtin_nontemporal_load(
                (const i32x4*)(W + (size_t)(k0 + r) * N_DIM + n0 + c));
            tile[r][c] = v.x; tile[r][c + 1] = v.y; tile[r][c + 2] = v.z; tile[r][c + 3] = v.w;
        }
        __syncthreads();
        {   // thread t: row n = t>>2, k-span (t&3)*16 .. +16  (two 16B stores, cached)
            int n = t >> 2, ks = (t & 3) * 16;
            __align__(16) u16 o[16];
#pragma unroll
            for (int i = 0; i < 16; i++)
                o[i] = f2bf((float)tile[ks + i][n]);
            u16* dst = Wt + (size_t)(n0 + n) * K_DIM + k0 + ks;
            *(uint4*)(dst)     = *(const uint4*)&o[0];
            *(uint4*)(dst + 8) = *(const uint4*)&o[8];
        }
    } else {
        // X convert: block covers 4096 float4 = 64 KB; 8 iters x 512 float4
        const size_t base = (size_t)(bid - 4096) * 4096;
        const f32x4*   x4 = (const f32x4*)X;
        u16x4*         o4 = (u16x4*)Xb;               // u16x4 index == float4 index
#pragma unroll
        for (int it = 0; it < 8; it++) {
            size_t ia = base + (size_t)it * 512 + t;  // lanes contiguous -> coalesced
            size_t ib = ia + 256;
            f32x4 a = __builtin_nontemporal_load(x4 + ia);
            f32x4 b = __builtin_nontemporal_load(x4 + ib);
            u16x4 oa, ob;
            oa.x = f2bf(a.x); oa.y = f2bf(a.y); oa.z = f2bf(a.z); oa.w = f2bf(a.w);
            ob.x = f2bf(b.x); ob.y = f2bf(b.y); ob.z = f2bf(b.z); ob.w = f2bf(b.w);
            o4[ia] = oa;                              // cached: gemm reads these next
            o4[ib] = ob;
        }
    }
}

// =====================================================================
// 256x256 GEMM, R4 = R1's proven structure (245.5us / 50.2% MfmaUtil;
// R2/R3's read-ahead restructures both regressed to 41% and are abandoned)
// + ONE delta: fragment-read REBALANCING within R1's windows.
//
// R1 read counts per phase were 12/4/8/0 (ph1 carried a0[4]+b0[2] = 12
// ds_read_b128 on the critical path). New schedule: 4/8/4/8 with ph4's 8
// issued AFTER the MFMA cluster + VMCNT (they fill the barrier wait):
//   ph1: a0_hi(T)        ph2: b1(T) + a1_lo(T)   ph3: a1_hi(T)
//   ph4 (post-VMCNT(6)): b0(T+1) + a0_lo(T+1)    [cross-tile, PRE flag]
// Landing proof: VMCNT(6)@ph4(T-1) leaves only {A_lo,B_lo,B_hi}(T+1) in
// flight -> everything through A_hi(T) landed -> all tile-T reads (issued
// ph4(T-1)..ph3(T)) see landed data; ph4(T)'s cross-tile reads need
// A_lo/B_lo(T+1), which are issue-OLDER than A_hi(T+1) (the vmcnt target).
// Stale-read/overwrite: each region's reads drain at a per-wave lgkm0 >=1
// barrier before its re-stage (A_lo: drain ph1 lgkm0 -> S2@ph2; B_lo:
// ph1 -> S3@ph3; B_hi: ph2 -> S4@ph4; A_hi: ph3 -> S1@ph1(T+1)).
// Registers: b0/a0_lo overwritten @ph4, last used @ph3/ph2; a1_lo
// overwritten @ph2(T+1), last used @ph4(T).
// =====================================================================

#define BK 64
#define NT (K_DIM / BK)
static_assert(NT >= 6 && (NT & 1) == 0, "tile count must be even and >= 6");

#define BARRIER() do { asm volatile("" ::: "memory"); \
                       __builtin_amdgcn_s_barrier();  \
                       asm volatile("" ::: "memory"); } while (0)
#define WAIT_LGKM() asm volatile("s_waitcnt lgkmcnt(0)" ::: "memory")
#define VMCNT(n)    asm volatile("s_waitcnt vmcnt(" #n ")" ::: "memory")

// fragment reads (ds_read_b128, swizzled). A split in lo/hi halves (2 each).
#define READ_A_LO(dst, base, mhv)                                                 \
    _Pragma("unroll") for (int i = 0; i < 2; i++) {                               \
        const char* p_ = (base) + ((mhv) * 128 + wrow * 64 + i * 16 + fr) * 128;  \
        _Pragma("unroll") for (int kk = 0; kk < 2; kk++)                          \
            dst[i][kk] = *(const bf16x8*)(p_ + ((kk * 64 + fk2) ^ sw));           \
    }
#define READ_A_HI(dst, base, mhv)                                                 \
    _Pragma("unroll") for (int i = 2; i < 4; i++) {                               \
        const char* p_ = (base) + ((mhv) * 128 + wrow * 64 + i * 16 + fr) * 128;  \
        _Pragma("unroll") for (int kk = 0; kk < 2; kk++)                          \
            dst[i][kk] = *(const bf16x8*)(p_ + ((kk * 64 + fk2) ^ sw));           \
    }
#define READ_B(dst, base, nhv)                                                    \
    _Pragma("unroll") for (int j = 0; j < 2; j++) {                               \
        const char* p_ = (base) + ((nhv) * 128 + wcol * 32 + j * 16 + fr) * 128;  \
        _Pragma("unroll") for (int kk = 0; kk < 2; kk++)                          \
            dst[j][kk] = *(const bf16x8*)(p_ + ((kk * 64 + fk2) ^ sw));           \
    }

#define MFMA_Q(MH, NH, aarr, barr)                                                \
    do {                                                                          \
        __builtin_amdgcn_s_setprio(1);                                            \
        _Pragma("unroll") for (int kk = 0; kk < 2; kk++)                          \
            _Pragma("unroll") for (int i = 0; i < 4; i++)                         \
                _Pragma("unroll") for (int j = 0; j < 2; j++)                     \
                    acc[MH][NH][i][j] = __builtin_amdgcn_mfma_f32_16x16x32_bf16(  \
                        aarr[i][kk], barr[j][kk], acc[MH][NH][i][j], 0, 0, 0);    \
        __builtin_amdgcn_s_setprio(0);                                            \
    } while (0)

// stage one half-tile (128 rows x 64 cols bf16 = 16 KiB) = 2 x global_load_lds.
// LDS dest linear (wave-uniform base + lane*16); swizzle pre-applied to the
// per-lane GLOBAL source address (aoffN encodes chunk ^= row&7).
#define STAGE_A(bufv, h, kt)                                                      \
    do {                                                                          \
        const u16* g_ = gA + (size_t)(h) * (128 * K_DIM) + (size_t)(kt) * 64;     \
        char* l_ = (char*)lds + (bufv) * 32768 + (h) * 16384 + wv * 1024;         \
        __builtin_amdgcn_global_load_lds(GLOBAL_AS(g_ + aoff0), LDS_AS(l_), 16, 0, 0);        \
        __builtin_amdgcn_global_load_lds(GLOBAL_AS(g_ + aoff1), LDS_AS(l_ + 8192), 16, 0, 0); \
    } while (0)

#define STAGE_B(bufv, h, kt)                                                      \
    do {                                                                          \
        const u16* g_ = gB + (size_t)(h) * (128 * K_DIM) + (size_t)(kt) * 64;     \
        char* l_ = (char*)lds + 65536 + (bufv) * 32768 + (h) * 16384 + wv * 1024; \
        __builtin_amdgcn_global_load_lds(GLOBAL_AS(g_ + aoff0), LDS_AS(l_), 16, 0, 0);        \
        __builtin_amdgcn_global_load_lds(GLOBAL_AS(g_ + aoff1), LDS_AS(l_ + 8192), 16, 0, 0); \
    } while (0)

// one K-tile = 4 phases, R1's two-barriers-per-phase structure.
// S1..S4: stage statements; SYNC: per-tile counted vmcnt (end of ph4);
// PRE: cross-tile ph4 reads (off on the last tile).
#define TILE(bv, S1, S2, S3, S4, SYNC, PRE)                                       \
    {                                                                             \
        const char* As_ = (const char*)lds + (bv) * 32768;                        \
        const char* Bs_ = (const char*)lds + 65536 + (bv) * 32768;                \
        const char* An_ = (const char*)lds + ((bv) ^ 1) * 32768;                  \
        const char* Bn_ = (const char*)lds + 65536 + ((bv) ^ 1) * 32768;          \
        /* ph1 */                                                                 \
        READ_A_HI(a0, As_, 0);                                                    \
        S1;                                                                       \
        BARRIER(); WAIT_LGKM();                                                   \
        MFMA_Q(0, 0, a0, b0);                                                     \
        BARRIER();                                                                \
        /* ph2 */                                                                 \
        READ_B(b1, Bs_, 1);                                                       \
        READ_A_LO(a1, As_, 1);                                                    \
        S2;                                                                       \
        BARRIER(); WAIT_LGKM();                                                   \
        MFMA_Q(0, 1, a0, b1);                                                     \
        BARRIER();                                                                \
        /* ph3 */                                                                 \
        READ_A_HI(a1, As_, 1);                                                    \
        S3;                                                                       \
        BARRIER(); WAIT_LGKM();                                                   \
        MFMA_Q(1, 0, a1, b0);                                                     \
        BARRIER();                                                                \
        /* ph4 */                                                                 \
        S4;                                                                       \
        BARRIER();                                                                \
        MFMA_Q(1, 1, a1, b1);                                                     \
        SYNC;                                                                     \
        if (PRE) { READ_B(b0, Bn_, 0); READ_A_LO(a0, An_, 0); }                   \
        BARRIER();                                                                \
    }

__global__ __launch_bounds__(512, 2) void gemm_bf16_kernel(const u16* __restrict__ A,
                                                           const u16* __restrict__ Bt,
                                                           const float* __restrict__ scale_p,
                                                           float* __restrict__ C) {
    __shared__ __align__(16) u16 lds[65536];   // 128 KiB: A[2][256][64] | B[2][256][64]

    const int tid  = threadIdx.x;
    const int lane = tid & 63;
    const int wv   = tid >> 6;       // wave 0..7
    const int wrow = wv >> 2;        // 0..1  (M)
    const int wcol = wv & 3;         // 0..3  (N)

    // T1: bijective XCD swizzle, 512 blocks, 8 XCDs -> 64 blocks per XCD chunk
    const int bid = blockIdx.x;
    const int wg  = ((bid & 7) << 6) | (bid >> 3);
    const size_t m0 = (size_t)(wg >> 4) * 256;   // 32 M-tiles
    const size_t n0 = (size_t)(wg & 15) * 256;   // 16 N-tiles

    // fragment addressing: row r has swizzle XOR (r&7)<<4; frag rows are
    // multiple-of-16 + (lane&15) so the XOR is the per-lane constant sw.
    const int fr  = lane & 15;
    const int fk2 = (lane >> 4) * 16;            // k byte offset {0,16,32,48}
    const int sw  = (lane & 7) << 4;

    // staging: half-tile chunk q in {tid, tid+512}; row = q>>3,
    // global chunk = (q&7) ^ (row&7)  (inverse swizzle on the source side)
    const int q0 = tid,       r0 = q0 >> 3, c0 = (q0 & 7) ^ (r0 & 7);
    const int q1 = tid + 512, r1 = q1 >> 3, c1 = (q1 & 7) ^ (r1 & 7);
    const size_t aoff0 = (size_t)r0 * K_DIM + c0 * 8;
    const size_t aoff1 = (size_t)r1 * K_DIM + c1 * 8;

    const u16* gA = A  + m0 * K_DIM;
    const u16* gB = Bt + n0 * K_DIM;

    f32x4 acc[2][2][4][2] = {};
    bf16x8 a0[4][2], a1[4][2], b0[2][2], b1[2][2];

    // prologue: stage tiles 0 and 1 completely (16 loads)
    STAGE_A(0, 0, 0); STAGE_B(0, 0, 0); STAGE_B(0, 1, 0); STAGE_A(0, 1, 0);
    STAGE_A(1, 0, 1); STAGE_B(1, 0, 1); STAGE_B(1, 1, 1); STAGE_A(1, 1, 1);
    VMCNT(8);            // tile 0 landed; tile 1's 8 loads stay in flight
    BARRIER();
    {   // preload tile 0's ph1 operands matching steady state: b0 + a0_lo
        const char* As_ = (const char*)lds;
        const char* Bs_ = (const char*)lds + 65536;
        READ_B(b0, Bs_, 0);
        READ_A_LO(a0, As_, 0);
    }
    WAIT_LGKM();         // drain preloads before any wave's staging can overwrite

    // main loop: tiles 0..NT-3 in pairs; stage schedule identical to R1
    for (int T = 0; T < NT - 2; T += 2) {
        TILE(0,
             STAGE_A(1, 1, T + 1), STAGE_A(0, 0, T + 2),
             STAGE_B(0, 0, T + 2), STAGE_B(0, 1, T + 2),
             VMCNT(6), 1);
        TILE(1,
             STAGE_A(0, 1, T + 2), STAGE_A(1, 0, T + 3),
             STAGE_B(1, 0, T + 3), STAGE_B(1, 1, T + 3),
             VMCNT(6), 1);
    }
    // tile NT-2 (buf 0): only A_hi(NT-1) remains; full drain before cross-reads
    TILE(0, STAGE_A(1, 1, NT - 1), (void)0, (void)0, (void)0, VMCNT(0), 1);
    // tile NT-1 (buf 1): pure compute, no prefetch
    TILE(1, (void)0, (void)0, (void)0, (void)0, (void)0, 0);

    // epilogue: D layout col = lane&15, row = (lane>>4)*4 + reg; NT stores
    const float s = *scale_p;
    const int ec = lane & 15;
    const int er = (lane >> 4) * 4;
#pragma unroll
    for (int mh = 0; mh < 2; mh++)
#pragma unroll
        for (int nh = 0; nh < 2; nh++)
#pragma unroll
            for (int i = 0; i < 4; i++)
#pragma unroll
                for (int j = 0; j < 2; j++) {
                    float* cp = C + (m0 + mh * 128 + wrow * 64 + i * 16 + er) * N_DIM
                                  + (n0 + nh * 128 + wcol * 32 + j * 16 + ec);
#pragma unroll
                    for (int r = 0; r < 4; r++)
                        __builtin_nontemporal_store(acc[mh][nh][i][j][r] * s,
                                                    cp + (size_t)r * N_DIM);
                }
}

// ---------- fallback fp32 GEMM (only if ws too small; correctness net) ----------
__global__ __launch_bounds__(256) void fb_gemm_kernel(const float* __restrict__ X,
                                                      const int* __restrict__ W,
                                                      const float* __restrict__ sp,
                                                      float* __restrict__ Y) {
    __shared__ float Xs[16][64];
    __shared__ float Ws[16][64];
    const int t = threadIdx.x;
    const int tx = t & 15, ty = t >> 4;
    const int m0 = blockIdx.y * 64, n0 = blockIdx.x * 64;
    float acc[4][4] = {};
    for (int k0 = 0; k0 < K_DIM; k0 += 16) {
#pragma unroll
        for (int i = 0; i < 4; i++) {
            int e = t + i * 256;
            int r = e >> 4, c = e & 15;
            Xs[c][r] = X[(size_t)(m0 + r) * K_DIM + k0 + c];
            int rw = e >> 6, cw = e & 63;
            Ws[rw][cw] = (float)W[(size_t)(k0 + rw) * N_DIM + n0 + cw];
        }
        __syncthreads();
#pragma unroll
        for (int kk = 0; kk < 16; kk++)
#pragma unroll
            for (int i = 0; i < 4; i++)
#pragma unroll
                for (int j = 0; j < 4; j++)
                    acc[i][j] += Xs[kk][ty * 4 + i] * Ws[kk][tx * 4 + j];
        __syncthreads();
    }
    const float s = *sp;
#pragma unroll
    for (int i = 0; i < 4; i++)
#pragma unroll
        for (int j = 0; j < 4; j++)
            Y[(size_t)(m0 + ty * 4 + i) * N_DIM + n0 + tx * 4 + j] = acc[i][j] * s;
}

extern "C" void kernel_launch(void* const* d_in, const int* in_sizes, int n_in,
                              void* d_out, int out_size, void* d_ws, size_t ws_size,
                              hipStream_t stream) {
    const float* X  = (const float*)d_in[0];
    const int*   W  = (const int*)d_in[1];
    const float* sp = (const float*)d_in[2];
    float* Y = (float*)d_out;

    const size_t xb = (size_t)M_DIM * K_DIM * sizeof(u16);   // 64 MB
    const size_t wb = (size_t)N_DIM * K_DIM * sizeof(u16);   // 32 MB

    if (ws_size >= xb + wb) {
        u16* Xb = (u16*)d_ws;
        u16* Wt = (u16*)((char*)d_ws + xb);
        prepass_kernel<<<6144, 256, 0, stream>>>(X, W, Xb, Wt);
        gemm_bf16_kernel<<<512, 512, 0, stream>>>(Xb, Wt, sp, Y);
    } else {
        fb_gemm_kernel<<<dim3(N_DIM / 64, M_DIM / 64), 256, 0, stream>>>(X, W, sp, Y);
    }
}